// Round 9
// baseline (366.772 us; speedup 1.0000x reference)
//
#include <hip/hip_runtime.h>
#include <hip/hip_cooperative_groups.h>
#include <hip/hip_bf16.h>

namespace cg = cooperative_groups;

#define Bb 2
#define Nn 2048
#define Ee 256
#define Hh 4
#define DKk 64

typedef __bf16 bf16x8 __attribute__((ext_vector_type(8)));
typedef float f32x4 __attribute__((ext_vector_type(4)));

// QSCALE = (1/sqrt(64)) * log2(e): folded into Wq so scores come out of the
// MFMA already in exp2 domain. MOFF folded into MFMA C init (free subtract).
#define QSCALE 0.18033688011112042f
#define MOFF 20.0f

// ---------------- single cooperative kernel: pack -> qkv -> attn -> outproj ----
// Grid 256 x 512 threads: one block per CU (co-resident for grid.sync at any
// VGPR count: 8 waves x ~200 VGPR << per-CU pool). Phases separated by
// __threadfence() + grid.sync() (device-scope fence: per-XCD L2 non-coherence,
// G16). Eliminates 3 kernel-launch boundaries; makes the whole pipeline ONE
// dispatch so its counters are finally visible above the 44-us fill wall.
__global__ void __launch_bounds__(512) fused_all(
        const int* __restrict__ adj,
        unsigned long long* __restrict__ bits,
        const float* __restrict__ x,
        const float* __restrict__ Wq,
        const float* __restrict__ Wk,
        const float* __restrict__ Wv,
        const float* __restrict__ Wo,
        const float* __restrict__ bo,
        __bf16* __restrict__ xb,
        __bf16* __restrict__ WB,
        __bf16* __restrict__ WoB,
        __bf16* __restrict__ Qb,
        __bf16* __restrict__ Kf,
        __bf16* __restrict__ Vf,
        __bf16* __restrict__ heads,   // aliases xb (xb dead after phase 1)
        float* __restrict__ out) {
    cg::grid_group grid = cg::this_grid();

    int blk = blockIdx.x;            // 0..255
    int t = threadIdx.x;             // 0..511
    int wid = t >> 6, lane = t & 63, li = lane & 15, quad = lane >> 4;
    int w4 = wid & 3, sub = wid >> 2;

    __shared__ __align__(16) __bf16 PS[8][16][72];
    __shared__ float OL[8][16][68];
    __shared__ float lL[8][16];

    // ================= phase 0: adj bitmask + bf16 packing =================
    {
        // adj -> bits: 2048 waves, 16 groups each. Group = 256 keys -> 4 u64
        // words; word c bit l <-> key 4*l + c (attn lane li reads word li&3).
        #pragma unroll 4
        for (int i = 0; i < 16; ++i) {
            int gid = blk * 128 + wid * 16 + i;        // 0..32767
            int row = gid >> 3;                        // b*N + q
            int g = gid & 7;                           // 256-key group
            const int4* src = (const int4*)(adj + (size_t)row * Nn + g * 256) + lane;
            int4 v = *src;
            unsigned long long b0 = __ballot(v.x > 0);
            unsigned long long b1 = __ballot(v.y > 0);
            unsigned long long b2 = __ballot(v.z > 0);
            unsigned long long b3 = __ballot(v.w > 0);
            if (lane == 0) {
                ulonglong2* dst = (ulonglong2*)(bits + (size_t)gid * 4);
                ulonglong2 p0; p0.x = b0; p0.y = b1;
                ulonglong2 p1; p1.x = b2; p1.y = b3;
                dst[0] = p0;
                dst[1] = p1;
            }
        }
        int tid = blk * 512 + t;                       // 0..131071
        // x -> xb (bf16): 262144 float4 items, 2 per thread
        #pragma unroll
        for (int j = 0; j < 2; ++j) {
            size_t i = ((size_t)(tid + j * 131072)) * 4;
            float4 v = *(const float4*)(x + i);
            __bf16 o4[4] = {(__bf16)v.x, (__bf16)v.y, (__bf16)v.z, (__bf16)v.w};
            *(ushort4*)(xb + i) = *(ushort4*)o4;
        }
        // Wq/Wk/Wv -> WB rows (m*4+h)*64+e, transposed, Wq pre-scaled
        #pragma unroll
        for (int j = 0; j < 2; ++j) {
            int id = tid + j * 131072;
            if (id < 196608) {
                int row = id >> 8, col = id & 255;     // row 0..767
                int m = row >> 8, h = (row >> 6) & 3, e = row & 63;
                const float* W = (m == 0 ? Wq : (m == 1 ? Wk : Wv));
                float sc = (m == 0) ? QSCALE : 1.0f;
                WB[(size_t)row * 256 + col] = (__bf16)(W[h * 16384 + col * 64 + e] * sc);
            }
        }
        // Wo -> WoB: 16384 float4 items
        if (tid < 16384) {
            size_t i = (size_t)tid * 4;
            float4 v = *(const float4*)(Wo + i);
            __bf16 o4[4] = {(__bf16)v.x, (__bf16)v.y, (__bf16)v.z, (__bf16)v.w};
            *(ushort4*)(WoB + i) = *(ushort4*)o4;
        }
    }
    __threadfence();
    grid.sync();

    // ================= phase 1: QKV projection =================
    // xb:(4096,256) @ WB(768,256)^T. Two 4-wave sub-blocks split the 12
    // col-tiles 6/6 (sub = former "half"). Q row-major; K/V to fragment order.
    {
        int row0 = blk * 16;
        bf16x8 a[8];
        const __bf16* ap = xb + (size_t)(row0 + li) * 256 + quad * 8;
        #pragma unroll
        for (int i = 0; i < 8; ++i) a[i] = *(const bf16x8*)(ap + i * 32);

        int b = row0 >> 11;
        int nloc = row0 & 2047;

        #pragma unroll 1
        for (int j = 0; j < 6; ++j) {
            int c0 = w4 * 192 + sub * 96 + j * 16;
            const __bf16* bp = WB + (size_t)(c0 + li) * 256 + quad * 8;
            f32x4 acc = (f32x4){0.f, 0.f, 0.f, 0.f};
            #pragma unroll
            for (int i = 0; i < 8; ++i) {
                bf16x8 bfrag = *(const bf16x8*)(bp + i * 32);
                acc = __builtin_amdgcn_mfma_f32_16x16x32_bf16(a[i], bfrag, acc, 0, 0, 0);
            }
            int m = c0 >> 8;                  // wave-uniform
            int h = (c0 >> 6) & 3;
            int e0 = c0 & 63;
            int bh = b * 4 + h;
            if (m == 0) {
                size_t base = ((size_t)bh * Nn + nloc + quad * 4) * 64 + e0 + li;
                #pragma unroll
                for (int r = 0; r < 4; ++r) Qb[base + (size_t)r * 64] = (__bf16)acc[r];
            } else if (m == 1) {
                int e = e0 + li;
                int cp = e >> 5, ek = e & 31;
                int qA = ek >> 3, jA = ek & 7;
                int kt = nloc >> 4;
                size_t ub = (((size_t)(bh * 128 + kt)) * 2 + cp) * 512 + qA * 128 + jA;
                #pragma unroll
                for (int r = 0; r < 4; ++r) Kf[ub + (quad * 4 + r) * 8] = (__bf16)acc[r];
            } else {
                int e = e0 + li;
                int et = e >> 4, liA = e & 15;
                int key32 = nloc >> 5;
                int nnb = nloc & 16;
                size_t ub = (((size_t)(bh * 64 + key32)) * 4 + et) * 512 + liA * 8;
                #pragma unroll
                for (int r = 0; r < 4; ++r) {
                    int nn = nnb + quad * 4 + r;
                    Vf[ub + (nn >> 3) * 128 + (nn & 7)] = (__bf16)acc[r];
                }
            }
        }
    }
    __threadfence();
    grid.sync();

    // ================= phase 2: flash attention =================
    // bh = blk&7 (XCD head pinning), pp = blk>>3. Two 4-wave sub-blocks; each
    // handles q-tiles pp*4 + sub*2 + {0,1}; wave w4 owns key quarter w4.
    // Round-1 internals (measured best): per-tile kb/vb, setprio MFMA
    // clusters, hoisted u64 mask shift, static-max exp2-domain softmax.
    {
        int bh = blk & 7, pp = blk >> 3;
        int b = bh >> 2, h = bh & 3;
        const __bf16* Kfb = Kf + (size_t)bh * 131072;
        const __bf16* Vfb = Vf + (size_t)bh * 131072;
        int lanew = lane * 8;

        #pragma unroll 1
        for (int qi = 0; qi < 2; ++qi) {
            int q0 = (pp * 4 + sub * 2 + qi) * 16;

            const __bf16* qp = Qb + ((size_t)bh * Nn + q0 + li) * 64 + quad * 8;
            bf16x8 qa0 = *(const bf16x8*)qp;
            bf16x8 qa1 = *(const bf16x8*)(qp + 32);

            f32x4 o[4];
            #pragma unroll
            for (int et = 0; et < 4; ++et) o[et] = (f32x4){0.f, 0.f, 0.f, 0.f};
            f32x4 ls = (f32x4){0.f, 0.f, 0.f, 0.f};

            #pragma unroll 1
            for (int g = 0; g < 2; ++g) {
                int grp = w4 * 2 + g;                       // 256-key group 0..7
                unsigned long long aw[4];
                #pragma unroll
                for (int r = 0; r < 4; ++r)
                    aw[r] = bits[(((size_t)b * Nn + q0 + quad * 4 + r) * 8 + grp) * 4 + (li & 3)];

                #pragma unroll 1
                for (int tt = 0; tt < 4; ++tt) {
                    int key64 = grp * 4 + tt;               // 64-key tile 0..31

                    bf16x8 kb[4][2];
                    #pragma unroll
                    for (int nt = 0; nt < 4; ++nt)
                        #pragma unroll
                        for (int c = 0; c < 2; ++c)
                            kb[nt][c] = *(const bf16x8*)(Kfb + ((size_t)((key64 * 4 + nt) * 2 + c)) * 512 + lanew);
                    bf16x8 vb[4][2];
                    #pragma unroll
                    for (int et = 0; et < 4; ++et)
                        #pragma unroll
                        for (int kc = 0; kc < 2; ++kc)
                            vb[et][kc] = *(const bf16x8*)(Vfb + ((size_t)((key64 * 2 + kc) * 4 + et)) * 512 + lanew);

                    f32x4 s[4];
                    __builtin_amdgcn_s_setprio(1);
                    #pragma unroll
                    for (int nt = 0; nt < 4; ++nt) {
                        f32x4 z = (f32x4){-MOFF, -MOFF, -MOFF, -MOFF};
                        z = __builtin_amdgcn_mfma_f32_16x16x32_bf16(qa0, kb[nt][0], z, 0, 0, 0);
                        s[nt] = __builtin_amdgcn_mfma_f32_16x16x32_bf16(qa1, kb[nt][1], z, 0, 0, 0);
                    }
                    __builtin_amdgcn_s_setprio(0);

                    int shb = tt * 16 + (li >> 2);
                    unsigned awt[4];
                    #pragma unroll
                    for (int r = 0; r < 4; ++r) awt[r] = (unsigned)(aw[r] >> shb);

                    #pragma unroll
                    for (int nt = 0; nt < 4; ++nt) {
                        #pragma unroll
                        for (int r = 0; r < 4; ++r) {
                            unsigned bit = (awt[r] >> (nt * 4)) & 1u;
                            float p = bit ? __builtin_amdgcn_exp2f(s[nt][r]) : 0.f;
                            ls[r] += p;
                            PS[wid][quad * 4 + r][nt * 16 + li] = (__bf16)p;
                        }
                    }

                    // PS[wid] is per-wave: same-wave write->read, no barrier
                    bf16x8 pa0 = *(const bf16x8*)&PS[wid][li][quad * 8];
                    bf16x8 pa1 = *(const bf16x8*)&PS[wid][li][quad * 8 + 32];

                    __builtin_amdgcn_s_setprio(1);
                    #pragma unroll
                    for (int et = 0; et < 4; ++et) {
                        o[et] = __builtin_amdgcn_mfma_f32_16x16x32_bf16(pa0, vb[et][0], o[et], 0, 0, 0);
                        o[et] = __builtin_amdgcn_mfma_f32_16x16x32_bf16(pa1, vb[et][1], o[et], 0, 0, 0);
                    }
                    __builtin_amdgcn_s_setprio(0);
                }
            }

            // epilogue: reduce l over li lanes; merge this sub's 4 key-quarter
            // waves. Both subs hit the same barrier count per qi iteration.
            #pragma unroll
            for (int r = 0; r < 4; ++r) {
                float v = ls[r];
                v += __shfl_xor(v, 1, 64);
                v += __shfl_xor(v, 2, 64);
                v += __shfl_xor(v, 4, 64);
                v += __shfl_xor(v, 8, 64);
                if (li == 0) lL[wid][quad * 4 + r] = v;
                #pragma unroll
                for (int et = 0; et < 4; ++et)
                    OL[wid][quad * 4 + r][et * 16 + li] = o[et][r];
            }
            __syncthreads();

            int tl = t & 255;                 // thread within own sub-block
            int qrow = tl >> 4, e0 = (tl & 15) * 4;
            int wb0 = sub * 4;
            float l = lL[wb0][qrow] + lL[wb0 + 1][qrow] + lL[wb0 + 2][qrow] + lL[wb0 + 3][qrow];
            float inv = 1.0f / l;
            float s0 = 0.f, s1 = 0.f, s2 = 0.f, s3 = 0.f;
            #pragma unroll
            for (int w = 0; w < 4; ++w) {
                s0 += OL[wb0 + w][qrow][e0];
                s1 += OL[wb0 + w][qrow][e0 + 1];
                s2 += OL[wb0 + w][qrow][e0 + 2];
                s3 += OL[wb0 + w][qrow][e0 + 3];
            }
            __bf16 ob[4] = {(__bf16)(s0 * inv), (__bf16)(s1 * inv),
                            (__bf16)(s2 * inv), (__bf16)(s3 * inv)};
            __bf16* dst = heads + ((size_t)b * Nn + q0 + qrow) * 256 + h * 64 + e0;
            *(ushort4*)dst = *(ushort4*)ob;
            __syncthreads();   // OL/lL reads done before next qi overwrites
        }
    }
    __threadfence();
    grid.sync();

    // ================= phase 3: output projection =================
    // out = heads @ Wo^T + bo. Two sub-blocks split the 4 col-tiles 2/2.
    {
        int row0 = blk * 16;
        bf16x8 a[8];
        const __bf16* ap = heads + (size_t)(row0 + li) * 256 + quad * 8;
        #pragma unroll
        for (int i = 0; i < 8; ++i) a[i] = *(const bf16x8*)(ap + i * 32);

        #pragma unroll 1
        for (int j = 0; j < 2; ++j) {
            int c0 = w4 * 64 + sub * 32 + j * 16;
            const __bf16* bp = WoB + (size_t)(c0 + li) * 256 + quad * 8;
            f32x4 acc = (f32x4){0.f, 0.f, 0.f, 0.f};
            #pragma unroll
            for (int i = 0; i < 8; ++i) {
                bf16x8 bfrag = *(const bf16x8*)(bp + i * 32);
                acc = __builtin_amdgcn_mfma_f32_16x16x32_bf16(a[i], bfrag, acc, 0, 0, 0);
            }
            int c = c0 + li;
            float bias = bo[c];
            size_t base = ((size_t)row0 + quad * 4) * 256 + c;
            #pragma unroll
            for (int r = 0; r < 4; ++r) out[base + (size_t)r * 256] = acc[r] + bias;
        }
    }
}

extern "C" void kernel_launch(void* const* d_in, const int* in_sizes, int n_in,
                              void* d_out, int out_size, void* d_ws, size_t ws_size,
                              hipStream_t stream) {
    const float* x   = (const float*)d_in[0];
    const int*   adj = (const int*)d_in[1];
    const float* Wq  = (const float*)d_in[2];
    const float* Wk  = (const float*)d_in[3];
    const float* Wv  = (const float*)d_in[4];
    const float* Wo  = (const float*)d_in[5];
    const float* bo  = (const float*)d_in[6];
    float* out = (float*)d_out;

    char* ws = (char*)d_ws;
    const size_t MB = 1024 * 1024;
    __bf16* Qb  = (__bf16*)(ws);                         // 0-2 MB
    __bf16* Kf  = (__bf16*)(ws + 2 * MB);                // 2-4 MB
    __bf16* Vf  = (__bf16*)(ws + 4 * MB);                // 4-6 MB
    unsigned long long* bits = (unsigned long long*)(ws + 6 * MB);  // 6-7 MB
    __bf16* xb  = (__bf16*)(ws + 7 * MB);                // 7-9 MB (reused as heads)
    __bf16* WB  = (__bf16*)(ws + 9 * MB);                // 384 KB
    __bf16* WoB = (__bf16*)(ws + 9 * MB + 512 * 1024);   // 128 KB
    __bf16* headsb = xb;  // xb fully consumed in phase 1 (pre-grid.sync)

    void* args[] = {
        (void*)&adj, (void*)&bits, (void*)&x, (void*)&Wq, (void*)&Wk,
        (void*)&Wv, (void*)&Wo, (void*)&bo, (void*)&xb, (void*)&WB,
        (void*)&WoB, (void*)&Qb, (void*)&Kf, (void*)&Vf, (void*)&headsb,
        (void*)&out
    };
    hipLaunchCooperativeKernel((const void*)fused_all, dim3(256), dim3(512),
                               args, 0, stream);
}

// Round 13
// 141.838 us; speedup vs baseline: 2.5859x; 2.5859x over previous
//
#include <hip/hip_runtime.h>
#include <hip/hip_bf16.h>
#include <math.h>

#define Bb 2
#define Nn 2048
#define Ee 256
#define Hh 4
#define DKk 64

typedef __bf16 bf16x8 __attribute__((ext_vector_type(8)));
typedef float f32x4 __attribute__((ext_vector_type(4)));

// QSCALE = (1/sqrt(64)) * log2(e): folded into Wq so scores come out of the
// MFMA already in exp2 domain. MOFF folded into MFMA C init (free subtract).
#define QSCALE 0.18033688011112042f
#define MOFF 20.0f

// ---------------- fused: adjacency -> bitmask  +  bf16 packing ----------------
__global__ void __launch_bounds__(256) pack_fused(
        const int* __restrict__ adj,
        unsigned long long* __restrict__ bits,
        const float* __restrict__ x,
        const float* __restrict__ Wq,
        const float* __restrict__ Wk,
        const float* __restrict__ Wv,
        const float* __restrict__ Wo,
        __bf16* __restrict__ xb,
        __bf16* __restrict__ WB,
        __bf16* __restrict__ WoB) {
    int blk = blockIdx.x;
    int t = threadIdx.x;
    if (blk < 2048) {
        int wid = t >> 6, lane = t & 63;
        #pragma unroll
        for (int i = 0; i < 4; ++i) {
            int gid = blk * 16 + i * 4 + wid;          // 0..32767
            int row = gid >> 3;                        // b*N + q
            int g = gid & 7;                           // 256-key group
            const int4* src = (const int4*)(adj + (size_t)row * Nn + g * 256) + lane;
            int4 v = *src;
            unsigned long long b0 = __ballot(v.x > 0);
            unsigned long long b1 = __ballot(v.y > 0);
            unsigned long long b2 = __ballot(v.z > 0);
            unsigned long long b3 = __ballot(v.w > 0);
            if (lane == 0) {
                ulonglong2* dst = (ulonglong2*)(bits + (size_t)gid * 4);
                ulonglong2 p0; p0.x = b0; p0.y = b1;
                ulonglong2 p1; p1.x = b2; p1.y = b3;
                dst[0] = p0;
                dst[1] = p1;
            }
        }
    } else {
        int b2 = blk - 2048;
        if (b2 < 1024) {
            size_t i = ((size_t)b2 * 256 + t) * 4;
            float4 v = *(const float4*)(x + i);
            __bf16 o[4] = {(__bf16)v.x, (__bf16)v.y, (__bf16)v.z, (__bf16)v.w};
            *(ushort4*)(xb + i) = *(ushort4*)o;
        } else if (b2 < 1024 + 768) {
            int row = b2 - 1024;              // (m*4+h)*64 + e
            int m = row >> 8, h = (row >> 6) & 3, e = row & 63;
            const float* W = (m == 0 ? Wq : (m == 1 ? Wk : Wv));
            float sc = (m == 0) ? QSCALE : 1.0f;
            WB[(size_t)row * 256 + t] = (__bf16)(W[h * 16384 + t * 64 + e] * sc);
        } else {
            int b3 = b2 - 1792;
            size_t i = ((size_t)b3 * 256 + t) * 4;
            float4 v = *(const float4*)(Wo + i);
            __bf16 o[4] = {(__bf16)v.x, (__bf16)v.y, (__bf16)v.z, (__bf16)v.w};
            *(ushort4*)(WoB + i) = *(ushort4*)o;
        }
    }
}

// ---------------- QKV projection via MFMA ----------------
// xb:(4096,256) @ WB(768,256)^T. Q -> row-major (bh,n,dk).
// K -> Kf fragment order, V -> Vf fragment order (see attn).
// 1536 blocks: bm(256 row-stripes) x part(6 col-bands of 128). Wave wid covers
// 32 cols (2 c-tiles) -> 6 blocks/CU wanted, __launch_bounds__(256,4) caps
// VGPR at 128 for >=16 waves/CU. Fused-run evidence: phases are latency-bound
// and scale with waves/CU (was 2 waves/SIMD -> idle pipes).
__global__ void __launch_bounds__(256, 4) qkv_mfma(
        const __bf16* __restrict__ xb,
        const __bf16* __restrict__ WB,
        __bf16* __restrict__ Qb,
        __bf16* __restrict__ Kf,
        __bf16* __restrict__ Vf) {
    int blk = blockIdx.x;                // 1536 blocks
    int bm = blk / 6, part = blk % 6;
    int t = threadIdx.x;
    int wid = t >> 6, lane = t & 63, li = lane & 15, quad = lane >> 4;
    int row0 = bm * 16;

    bf16x8 a[8];
    const __bf16* ap = xb + (size_t)(row0 + li) * 256 + quad * 8;
    #pragma unroll
    for (int i = 0; i < 8; ++i) a[i] = *(const bf16x8*)(ap + i * 32);

    int b = row0 >> 11;
    int nloc = row0 & 2047;

    #pragma unroll 1
    for (int j = 0; j < 2; ++j) {
        int c0 = part * 128 + wid * 32 + j * 16;
        const __bf16* bp = WB + (size_t)(c0 + li) * 256 + quad * 8;
        f32x4 acc = (f32x4){0.f, 0.f, 0.f, 0.f};
        #pragma unroll
        for (int i = 0; i < 8; ++i) {
            bf16x8 bfrag = *(const bf16x8*)(bp + i * 32);
            acc = __builtin_amdgcn_mfma_f32_16x16x32_bf16(a[i], bfrag, acc, 0, 0, 0);
        }
        int m = c0 >> 8;                  // wave-uniform
        int h = (c0 >> 6) & 3;
        int e0 = c0 & 63;
        int bh = b * 4 + h;
        if (m == 0) {
            size_t base = ((size_t)bh * Nn + nloc + quad * 4) * 64 + e0 + li;
            #pragma unroll
            for (int r = 0; r < 4; ++r) Qb[base + (size_t)r * 64] = (__bf16)acc[r];
        } else if (m == 1) {
            int e = e0 + li;
            int cp = e >> 5, ek = e & 31;
            int qA = ek >> 3, jA = ek & 7;
            int kt = nloc >> 4;
            size_t ub = (((size_t)(bh * 128 + kt)) * 2 + cp) * 512 + qA * 128 + jA;
            #pragma unroll
            for (int r = 0; r < 4; ++r) Kf[ub + (quad * 4 + r) * 8] = (__bf16)acc[r];
        } else {
            int e = e0 + li;
            int et = e >> 4, liA = e & 15;
            int key32 = nloc >> 5;
            int nnb = nloc & 16;
            size_t ub = (((size_t)(bh * 64 + key32)) * 4 + et) * 512 + liA * 8;
            #pragma unroll
            for (int r = 0; r < 4; ++r) {
                int nn = nnb + quad * 4 + r;
                Vf[ub + (nn >> 3) * 128 + (nn & 7)] = (__bf16)acc[r];
            }
        }
    }
}

// ---------------- flash attention (Round-1 measured-best internals) ----------------
// Grid 1024, bh = blk&7 (XCD head pinning), qt = blk>>3. 4 waves; wave w owns
// key quarter w. setprio around MFMA clusters; hoisted u64 mask shift;
// static-max exp2-domain softmax. __launch_bounds__(256,3): 12 waves/CU.
__global__ void __launch_bounds__(256, 3) attn_kernel(
        const __bf16* __restrict__ Qb,
        const __bf16* __restrict__ Kf,
        const __bf16* __restrict__ Vf,
        const unsigned long long* __restrict__ bits,
        __bf16* __restrict__ heads) {
    __shared__ __align__(16) __bf16 PS[4][16][72];
    __shared__ float OL[4][16][68];
    __shared__ float lL[4][16];

    int blk = blockIdx.x;
    int bh = blk & 7, qt = blk >> 3;     // bijective: 1024 % 8 == 0
    int b = bh >> 2, h = bh & 3;
    int t = threadIdx.x;
    int wid = t >> 6, lane = t & 63, li = lane & 15, quad = lane >> 4;
    int q0 = qt * 16;

    const __bf16* qp = Qb + ((size_t)bh * Nn + q0 + li) * 64 + quad * 8;
    bf16x8 qa0 = *(const bf16x8*)qp;
    bf16x8 qa1 = *(const bf16x8*)(qp + 32);

    f32x4 o[4];
    #pragma unroll
    for (int et = 0; et < 4; ++et) o[et] = (f32x4){0.f, 0.f, 0.f, 0.f};
    f32x4 ls = (f32x4){0.f, 0.f, 0.f, 0.f};

    const __bf16* Kfb = Kf + (size_t)bh * 131072;
    const __bf16* Vfb = Vf + (size_t)bh * 131072;
    int lanew = lane * 8;

    #pragma unroll 1
    for (int g = 0; g < 2; ++g) {
        int grp = wid * 2 + g;                       // 256-key group 0..7
        unsigned long long aw[4];
        #pragma unroll
        for (int r = 0; r < 4; ++r)
            aw[r] = bits[(((size_t)b * Nn + q0 + quad * 4 + r) * 8 + grp) * 4 + (li & 3)];

        #pragma unroll 1
        for (int tt = 0; tt < 4; ++tt) {
            int key64 = grp * 4 + tt;                // 64-key tile 0..31

            bf16x8 kb[4][2];
            #pragma unroll
            for (int nt = 0; nt < 4; ++nt)
                #pragma unroll
                for (int c = 0; c < 2; ++c)
                    kb[nt][c] = *(const bf16x8*)(Kfb + ((size_t)((key64 * 4 + nt) * 2 + c)) * 512 + lanew);
            bf16x8 vb[4][2];
            #pragma unroll
            for (int et = 0; et < 4; ++et)
                #pragma unroll
                for (int kc = 0; kc < 2; ++kc)
                    vb[et][kc] = *(const bf16x8*)(Vfb + ((size_t)((key64 * 2 + kc) * 4 + et)) * 512 + lanew);

            f32x4 s[4];
            __builtin_amdgcn_s_setprio(1);
            #pragma unroll
            for (int nt = 0; nt < 4; ++nt) {
                f32x4 z = (f32x4){-MOFF, -MOFF, -MOFF, -MOFF};
                z = __builtin_amdgcn_mfma_f32_16x16x32_bf16(qa0, kb[nt][0], z, 0, 0, 0);
                s[nt] = __builtin_amdgcn_mfma_f32_16x16x32_bf16(qa1, kb[nt][1], z, 0, 0, 0);
            }
            __builtin_amdgcn_s_setprio(0);

            // hoisted 64-bit shift: one u64 shift per row, then 32-bit extracts
            int shb = tt * 16 + (li >> 2);
            unsigned awt[4];
            #pragma unroll
            for (int r = 0; r < 4; ++r) awt[r] = (unsigned)(aw[r] >> shb);

            #pragma unroll
            for (int nt = 0; nt < 4; ++nt) {
                #pragma unroll
                for (int r = 0; r < 4; ++r) {
                    unsigned bit = (awt[r] >> (nt * 4)) & 1u;
                    float p = bit ? __builtin_amdgcn_exp2f(s[nt][r]) : 0.f;
                    ls[r] += p;
                    PS[wid][quad * 4 + r][nt * 16 + li] = (__bf16)p;
                }
            }

            bf16x8 pa0 = *(const bf16x8*)&PS[wid][li][quad * 8];
            bf16x8 pa1 = *(const bf16x8*)&PS[wid][li][quad * 8 + 32];

            __builtin_amdgcn_s_setprio(1);
            #pragma unroll
            for (int et = 0; et < 4; ++et) {
                o[et] = __builtin_amdgcn_mfma_f32_16x16x32_bf16(pa0, vb[et][0], o[et], 0, 0, 0);
                o[et] = __builtin_amdgcn_mfma_f32_16x16x32_bf16(pa1, vb[et][1], o[et], 0, 0, 0);
            }
            __builtin_amdgcn_s_setprio(0);
        }
    }

    // per-wave epilogue: reduce l across the 16 li lanes, stash o + l in LDS
    #pragma unroll
    for (int r = 0; r < 4; ++r) {
        float v = ls[r];
        v += __shfl_xor(v, 1, 64);
        v += __shfl_xor(v, 2, 64);
        v += __shfl_xor(v, 4, 64);
        v += __shfl_xor(v, 8, 64);
        if (li == 0) lL[wid][quad * 4 + r] = v;
        #pragma unroll
        for (int et = 0; et < 4; ++et)
            OL[wid][quad * 4 + r][et * 16 + li] = o[et][r];
    }
    __syncthreads();

    // merge the 4 key quarters: pure sums (static offset shared by all waves)
    int qi = t >> 4, e0 = (t & 15) * 4;
    float l = lL[0][qi] + lL[1][qi] + lL[2][qi] + lL[3][qi];
    float inv = 1.0f / l;
    float s0 = 0.f, s1 = 0.f, s2 = 0.f, s3 = 0.f;
    #pragma unroll
    for (int w = 0; w < 4; ++w) {
        s0 += OL[w][qi][e0];
        s1 += OL[w][qi][e0 + 1];
        s2 += OL[w][qi][e0 + 2];
        s3 += OL[w][qi][e0 + 3];
    }
    __bf16 ob[4] = {(__bf16)(s0 * inv), (__bf16)(s1 * inv),
                    (__bf16)(s2 * inv), (__bf16)(s3 * inv)};
    __bf16* dst = heads + ((size_t)b * Nn + q0 + qi) * 256 + h * 64 + e0;
    *(ushort4*)dst = *(ushort4*)ob;
}

// ---------------- output projection via MFMA: out = heads @ Wo^T + bo ----------------
// 1024 blocks: bm(256) x part(4); each wave one 16-col tile -> 4 blocks/CU,
// 16 waves/CU (was 2 blocks/CU, 8 waves).
__global__ void __launch_bounds__(256, 4) outproj_mfma(
        const __bf16* __restrict__ hb,
        const __bf16* __restrict__ WoB,
        const float* __restrict__ bo,
        float* __restrict__ out) {
    int blk = blockIdx.x;                // 1024 blocks
    int bm = blk >> 2, part = blk & 3;
    int t = threadIdx.x;
    int wid = t >> 6, lane = t & 63, li = lane & 15, quad = lane >> 4;
    int row0 = bm * 16;

    bf16x8 a[8];
    const __bf16* ap = hb + (size_t)(row0 + li) * 256 + quad * 8;
    #pragma unroll
    for (int i = 0; i < 8; ++i) a[i] = *(const bf16x8*)(ap + i * 32);

    int c0 = part * 64 + wid * 16;
    const __bf16* bp = WoB + (size_t)(c0 + li) * 256 + quad * 8;
    f32x4 acc = (f32x4){0.f, 0.f, 0.f, 0.f};
    #pragma unroll
    for (int i = 0; i < 8; ++i) {
        bf16x8 bfrag = *(const bf16x8*)(bp + i * 32);
        acc = __builtin_amdgcn_mfma_f32_16x16x32_bf16(a[i], bfrag, acc, 0, 0, 0);
    }
    int c = c0 + li;
    float bias = bo[c];
    size_t base = ((size_t)row0 + quad * 4) * 256 + c;
    #pragma unroll
    for (int r = 0; r < 4; ++r) out[base + (size_t)r * 256] = acc[r] + bias;
}

extern "C" void kernel_launch(void* const* d_in, const int* in_sizes, int n_in,
                              void* d_out, int out_size, void* d_ws, size_t ws_size,
                              hipStream_t stream) {
    const float* x   = (const float*)d_in[0];
    const int*   adj = (const int*)d_in[1];
    const float* Wq  = (const float*)d_in[2];
    const float* Wk  = (const float*)d_in[3];
    const float* Wv  = (const float*)d_in[4];
    const float* Wo  = (const float*)d_in[5];
    const float* bo  = (const float*)d_in[6];
    float* out = (float*)d_out;

    char* ws = (char*)d_ws;
    const size_t MB = 1024 * 1024;
    __bf16* Qb  = (__bf16*)(ws);                         // 0-2 MB
    __bf16* Kf  = (__bf16*)(ws + 2 * MB);                // 2-4 MB
    __bf16* Vf  = (__bf16*)(ws + 4 * MB);                // 4-6 MB
    unsigned long long* bits = (unsigned long long*)(ws + 6 * MB);  // 6-7 MB
    __bf16* xb  = (__bf16*)(ws + 7 * MB);                // 7-9 MB (reused as heads)
    __bf16* WB  = (__bf16*)(ws + 9 * MB);                // 384 KB
    __bf16* WoB = (__bf16*)(ws + 9 * MB + 512 * 1024);   // 128 KB
    __bf16* headsb = xb;  // safe: xb only read by qkv_mfma, which precedes attn

    pack_fused<<<3904, 256, 0, stream>>>(adj, bits, x, Wq, Wk, Wv, Wo, xb, WB, WoB);
    qkv_mfma<<<1536, 256, 0, stream>>>(xb, WB, Qb, Kf, Vf);
    attn_kernel<<<1024, 256, 0, stream>>>(Qb, Kf, Vf, bits, headsb);
    outproj_mfma<<<1024, 256, 0, stream>>>(headsb, WoB, bo, out);
}

// Round 14
// 136.866 us; speedup vs baseline: 2.6798x; 1.0363x over previous
//
#include <hip/hip_runtime.h>
#include <hip/hip_bf16.h>
#include <math.h>

#define Bb 2
#define Nn 2048
#define Ee 256
#define Hh 4
#define DKk 64

typedef __bf16 bf16x8 __attribute__((ext_vector_type(8)));
typedef float f32x4 __attribute__((ext_vector_type(4)));

// QSCALE = (1/sqrt(64)) * log2(e): folded into Wq so scores come out of the
// MFMA already in exp2 domain. MOFF folded into MFMA C init (free subtract).
#define QSCALE 0.18033688011112042f
#define MOFF 20.0f

// ---------------- fused: adjacency -> bitmask  +  weight bf16 packing ----------------
// x is no longer packed: qkv_mfma reads f32 x directly (identical bf16
// rounding inline) -> this kernel drops from 3904 to 2880 blocks and the
// 6 MB xb round-trip disappears.
__global__ void __launch_bounds__(256) pack_fused(
        const int* __restrict__ adj,
        unsigned long long* __restrict__ bits,
        const float* __restrict__ Wq,
        const float* __restrict__ Wk,
        const float* __restrict__ Wv,
        const float* __restrict__ Wo,
        __bf16* __restrict__ WB,
        __bf16* __restrict__ WoB) {
    int blk = blockIdx.x;
    int t = threadIdx.x;
    if (blk < 2048) {
        int wid = t >> 6, lane = t & 63;
        #pragma unroll
        for (int i = 0; i < 4; ++i) {
            int gid = blk * 16 + i * 4 + wid;          // 0..32767
            int row = gid >> 3;                        // b*N + q
            int g = gid & 7;                           // 256-key group
            const int4* src = (const int4*)(adj + (size_t)row * Nn + g * 256) + lane;
            int4 v = *src;
            unsigned long long b0 = __ballot(v.x > 0);
            unsigned long long b1 = __ballot(v.y > 0);
            unsigned long long b2 = __ballot(v.z > 0);
            unsigned long long b3 = __ballot(v.w > 0);
            if (lane == 0) {
                ulonglong2* dst = (ulonglong2*)(bits + (size_t)gid * 4);
                ulonglong2 p0; p0.x = b0; p0.y = b1;
                ulonglong2 p1; p1.x = b2; p1.y = b3;
                dst[0] = p0;
                dst[1] = p1;
            }
        }
    } else {
        int b2 = blk - 2048;
        if (b2 < 768) {
            int row = b2;                     // (m*4+h)*64 + e
            int m = row >> 8, h = (row >> 6) & 3, e = row & 63;
            const float* W = (m == 0 ? Wq : (m == 1 ? Wk : Wv));
            float sc = (m == 0) ? QSCALE : 1.0f;
            WB[(size_t)row * 256 + t] = (__bf16)(W[h * 16384 + t * 64 + e] * sc);
        } else {
            int b3 = b2 - 768;                // 0..63
            size_t i = ((size_t)b3 * 256 + t) * 4;
            float4 v = *(const float4*)(Wo + i);
            __bf16 o[4] = {(__bf16)v.x, (__bf16)v.y, (__bf16)v.z, (__bf16)v.w};
            *(ushort4*)(WoB + i) = *(ushort4*)o;
        }
    }
}

// ---------------- QKV projection via MFMA ----------------
// x:(4096,256) f32 @ WB(768,256)^T. A-fragments converted f32->bf16 inline
// (x is L2/L3-hot; conversion matches the old pack rounding exactly).
// Q -> row-major (bh,n,dk). K -> Kf fragment order, V -> Vf fragment order.
// 512 blocks: 2 blocks share one 16-row stripe, splitting the 12 col-tiles 6/6
// (the best-measured configuration, 135.1 us).
__global__ void __launch_bounds__(256) qkv_mfma(
        const float* __restrict__ x,
        const __bf16* __restrict__ WB,
        __bf16* __restrict__ Qb,
        __bf16* __restrict__ Kf,
        __bf16* __restrict__ Vf) {
    int blk = blockIdx.x;                // 512 blocks
    int bm = blk >> 1, half = blk & 1;
    int t = threadIdx.x;
    int wid = t >> 6, lane = t & 63, li = lane & 15, quad = lane >> 4;
    int row0 = bm * 16;

    bf16x8 a[8];
    const float* ap = x + (size_t)(row0 + li) * 256 + quad * 8;
    #pragma unroll
    for (int i = 0; i < 8; ++i) {
        float4 v0 = *(const float4*)(ap + i * 32);
        float4 v1 = *(const float4*)(ap + i * 32 + 4);
        __bf16 tmp[8] = {(__bf16)v0.x, (__bf16)v0.y, (__bf16)v0.z, (__bf16)v0.w,
                         (__bf16)v1.x, (__bf16)v1.y, (__bf16)v1.z, (__bf16)v1.w};
        a[i] = *(const bf16x8*)tmp;
    }

    int b = row0 >> 11;
    int nloc = row0 & 2047;

    #pragma unroll 1
    for (int j = 0; j < 6; ++j) {
        int c0 = wid * 192 + half * 96 + j * 16;
        const __bf16* bp = WB + (size_t)(c0 + li) * 256 + quad * 8;
        f32x4 acc = (f32x4){0.f, 0.f, 0.f, 0.f};
        #pragma unroll
        for (int i = 0; i < 8; ++i) {
            bf16x8 bfrag = *(const bf16x8*)(bp + i * 32);
            acc = __builtin_amdgcn_mfma_f32_16x16x32_bf16(a[i], bfrag, acc, 0, 0, 0);
        }
        int m = c0 >> 8;                  // wave-uniform
        int h = (c0 >> 6) & 3;
        int e0 = c0 & 63;
        int bh = b * 4 + h;
        if (m == 0) {
            size_t base = ((size_t)bh * Nn + nloc + quad * 4) * 64 + e0 + li;
            #pragma unroll
            for (int r = 0; r < 4; ++r) Qb[base + (size_t)r * 64] = (__bf16)acc[r];
        } else if (m == 1) {
            int e = e0 + li;
            int cp = e >> 5, ek = e & 31;
            int qA = ek >> 3, jA = ek & 7;
            int kt = nloc >> 4;
            size_t ub = (((size_t)(bh * 128 + kt)) * 2 + cp) * 512 + qA * 128 + jA;
            #pragma unroll
            for (int r = 0; r < 4; ++r) Kf[ub + (quad * 4 + r) * 8] = (__bf16)acc[r];
        } else {
            int e = e0 + li;
            int et = e >> 4, liA = e & 15;
            int key32 = nloc >> 5;
            int nnb = nloc & 16;
            size_t ub = (((size_t)(bh * 64 + key32)) * 4 + et) * 512 + liA * 8;
            #pragma unroll
            for (int r = 0; r < 4; ++r) {
                int nn = nnb + quad * 4 + r;
                Vf[ub + (nn >> 3) * 128 + (nn & 7)] = (__bf16)acc[r];
            }
        }
    }
}

// ---------------- flash attention (best-measured internals, 135.1 us) ----------------
// Grid 1024, bh = blk&7 (XCD head pinning), qt = blk>>3. 4 waves; wave w owns
// key quarter w. setprio around MFMA clusters; hoisted u64 mask shift;
// static-max exp2-domain softmax. __launch_bounds__(256,3): 12 waves/CU.
__global__ void __launch_bounds__(256, 3) attn_kernel(
        const __bf16* __restrict__ Qb,
        const __bf16* __restrict__ Kf,
        const __bf16* __restrict__ Vf,
        const unsigned long long* __restrict__ bits,
        __bf16* __restrict__ heads) {
    __shared__ __align__(16) __bf16 PS[4][16][72];
    __shared__ float OL[4][16][68];
    __shared__ float lL[4][16];

    int blk = blockIdx.x;
    int bh = blk & 7, qt = blk >> 3;     // bijective: 1024 % 8 == 0
    int b = bh >> 2, h = bh & 3;
    int t = threadIdx.x;
    int wid = t >> 6, lane = t & 63, li = lane & 15, quad = lane >> 4;
    int q0 = qt * 16;

    const __bf16* qp = Qb + ((size_t)bh * Nn + q0 + li) * 64 + quad * 8;
    bf16x8 qa0 = *(const bf16x8*)qp;
    bf16x8 qa1 = *(const bf16x8*)(qp + 32);

    f32x4 o[4];
    #pragma unroll
    for (int et = 0; et < 4; ++et) o[et] = (f32x4){0.f, 0.f, 0.f, 0.f};
    f32x4 ls = (f32x4){0.f, 0.f, 0.f, 0.f};

    const __bf16* Kfb = Kf + (size_t)bh * 131072;
    const __bf16* Vfb = Vf + (size_t)bh * 131072;
    int lanew = lane * 8;

    #pragma unroll 1
    for (int g = 0; g < 2; ++g) {
        int grp = wid * 2 + g;                       // 256-key group 0..7
        unsigned long long aw[4];
        #pragma unroll
        for (int r = 0; r < 4; ++r)
            aw[r] = bits[(((size_t)b * Nn + q0 + quad * 4 + r) * 8 + grp) * 4 + (li & 3)];

        #pragma unroll 1
        for (int tt = 0; tt < 4; ++tt) {
            int key64 = grp * 4 + tt;                // 64-key tile 0..31

            bf16x8 kb[4][2];
            #pragma unroll
            for (int nt = 0; nt < 4; ++nt)
                #pragma unroll
                for (int c = 0; c < 2; ++c)
                    kb[nt][c] = *(const bf16x8*)(Kfb + ((size_t)((key64 * 4 + nt) * 2 + c)) * 512 + lanew);
            bf16x8 vb[4][2];
            #pragma unroll
            for (int et = 0; et < 4; ++et)
                #pragma unroll
                for (int kc = 0; kc < 2; ++kc)
                    vb[et][kc] = *(const bf16x8*)(Vfb + ((size_t)((key64 * 2 + kc) * 4 + et)) * 512 + lanew);

            f32x4 s[4];
            __builtin_amdgcn_s_setprio(1);
            #pragma unroll
            for (int nt = 0; nt < 4; ++nt) {
                f32x4 z = (f32x4){-MOFF, -MOFF, -MOFF, -MOFF};
                z = __builtin_amdgcn_mfma_f32_16x16x32_bf16(qa0, kb[nt][0], z, 0, 0, 0);
                s[nt] = __builtin_amdgcn_mfma_f32_16x16x32_bf16(qa1, kb[nt][1], z, 0, 0, 0);
            }
            __builtin_amdgcn_s_setprio(0);

            // hoisted 64-bit shift: one u64 shift per row, then 32-bit extracts
            int shb = tt * 16 + (li >> 2);
            unsigned awt[4];
            #pragma unroll
            for (int r = 0; r < 4; ++r) awt[r] = (unsigned)(aw[r] >> shb);

            #pragma unroll
            for (int nt = 0; nt < 4; ++nt) {
                #pragma unroll
                for (int r = 0; r < 4; ++r) {
                    unsigned bit = (awt[r] >> (nt * 4)) & 1u;
                    float p = bit ? __builtin_amdgcn_exp2f(s[nt][r]) : 0.f;
                    ls[r] += p;
                    PS[wid][quad * 4 + r][nt * 16 + li] = (__bf16)p;
                }
            }

            bf16x8 pa0 = *(const bf16x8*)&PS[wid][li][quad * 8];
            bf16x8 pa1 = *(const bf16x8*)&PS[wid][li][quad * 8 + 32];

            __builtin_amdgcn_s_setprio(1);
            #pragma unroll
            for (int et = 0; et < 4; ++et) {
                o[et] = __builtin_amdgcn_mfma_f32_16x16x32_bf16(pa0, vb[et][0], o[et], 0, 0, 0);
                o[et] = __builtin_amdgcn_mfma_f32_16x16x32_bf16(pa1, vb[et][1], o[et], 0, 0, 0);
            }
            __builtin_amdgcn_s_setprio(0);
        }
    }

    // per-wave epilogue: reduce l across the 16 li lanes, stash o + l in LDS
    #pragma unroll
    for (int r = 0; r < 4; ++r) {
        float v = ls[r];
        v += __shfl_xor(v, 1, 64);
        v += __shfl_xor(v, 2, 64);
        v += __shfl_xor(v, 4, 64);
        v += __shfl_xor(v, 8, 64);
        if (li == 0) lL[wid][quad * 4 + r] = v;
        #pragma unroll
        for (int et = 0; et < 4; ++et)
            OL[wid][quad * 4 + r][et * 16 + li] = o[et][r];
    }
    __syncthreads();

    // merge the 4 key quarters: pure sums (static offset shared by all waves)
    int qi = t >> 4, e0 = (t & 15) * 4;
    float l = lL[0][qi] + lL[1][qi] + lL[2][qi] + lL[3][qi];
    float inv = 1.0f / l;
    float s0 = 0.f, s1 = 0.f, s2 = 0.f, s3 = 0.f;
    #pragma unroll
    for (int w = 0; w < 4; ++w) {
        s0 += OL[w][qi][e0];
        s1 += OL[w][qi][e0 + 1];
        s2 += OL[w][qi][e0 + 2];
        s3 += OL[w][qi][e0 + 3];
    }
    __bf16 ob[4] = {(__bf16)(s0 * inv), (__bf16)(s1 * inv),
                    (__bf16)(s2 * inv), (__bf16)(s3 * inv)};
    __bf16* dst = heads + ((size_t)b * Nn + q0 + qi) * 256 + h * 64 + e0;
    *(ushort4*)dst = *(ushort4*)ob;
}

// ---------------- output projection via MFMA: out = heads @ Wo^T + bo ----------------
// 512 blocks: 2 blocks share a 16-row stripe, splitting 4 col-tiles 2/2
// (the best-measured configuration).
__global__ void __launch_bounds__(256) outproj_mfma(
        const __bf16* __restrict__ hb,
        const __bf16* __restrict__ WoB,
        const float* __restrict__ bo,
        float* __restrict__ out) {
    int blk = blockIdx.x;                // 512 blocks
    int bm = blk >> 1, half = blk & 1;
    int t = threadIdx.x;
    int wid = t >> 6, lane = t & 63, li = lane & 15, quad = lane >> 4;
    int row0 = bm * 16;

    bf16x8 a[8];
    const __bf16* ap = hb + (size_t)(row0 + li) * 256 + quad * 8;
    #pragma unroll
    for (int i = 0; i < 8; ++i) a[i] = *(const bf16x8*)(ap + i * 32);

    #pragma unroll 1
    for (int j = 0; j < 2; ++j) {
        int c0 = wid * 64 + half * 32 + j * 16;
        const __bf16* bp = WoB + (size_t)(c0 + li) * 256 + quad * 8;
        f32x4 acc = (f32x4){0.f, 0.f, 0.f, 0.f};
        #pragma unroll
        for (int i = 0; i < 8; ++i) {
            bf16x8 bfrag = *(const bf16x8*)(bp + i * 32);
            acc = __builtin_amdgcn_mfma_f32_16x16x32_bf16(a[i], bfrag, acc, 0, 0, 0);
        }
        int c = c0 + li;
        float bias = bo[c];
        size_t base = ((size_t)row0 + quad * 4) * 256 + c;
        #pragma unroll
        for (int r = 0; r < 4; ++r) out[base + (size_t)r * 256] = acc[r] + bias;
    }
}

extern "C" void kernel_launch(void* const* d_in, const int* in_sizes, int n_in,
                              void* d_out, int out_size, void* d_ws, size_t ws_size,
                              hipStream_t stream) {
    const float* x   = (const float*)d_in[0];
    const int*   adj = (const int*)d_in[1];
    const float* Wq  = (const float*)d_in[2];
    const float* Wk  = (const float*)d_in[3];
    const float* Wv  = (const float*)d_in[4];
    const float* Wo  = (const float*)d_in[5];
    const float* bo  = (const float*)d_in[6];
    float* out = (float*)d_out;

    char* ws = (char*)d_ws;
    const size_t MB = 1024 * 1024;
    __bf16* Qb  = (__bf16*)(ws);                         // 0-2 MB
    __bf16* Kf  = (__bf16*)(ws + 2 * MB);                // 2-4 MB
    __bf16* Vf  = (__bf16*)(ws + 4 * MB);                // 4-6 MB
    unsigned long long* bits = (unsigned long long*)(ws + 6 * MB);  // 6-7 MB
    __bf16* headsb = (__bf16*)(ws + 7 * MB);             // 7-9 MB
    __bf16* WB  = (__bf16*)(ws + 9 * MB);                // 384 KB
    __bf16* WoB = (__bf16*)(ws + 9 * MB + 512 * 1024);   // 128 KB

    pack_fused<<<2880, 256, 0, stream>>>(adj, bits, Wq, Wk, Wv, Wo, WB, WoB);
    qkv_mfma<<<512, 256, 0, stream>>>(x, WB, Qb, Kf, Vf);
    attn_kernel<<<1024, 256, 0, stream>>>(Qb, Kf, Vf, bits, headsb);
    outproj_mfma<<<512, 256, 0, stream>>>(headsb, WoB, bo, out);
}